// Round 1
// baseline (4049.318 us; speedup 1.0000x reference)
//
#include <hip/hip_runtime.h>
#include <stdint.h>
#include <stddef.h>

// ---------------------------------------------------------------------------
// Sparse top-2 MoE, bf16 MFMA compute, fp32 accumulate.
//   router: logits -> softmax -> top2 -> per-expert compact lists (+x->bf16)
//   GU:     h = silu(x@w1^T) * (x@w3^T)   (grouped GEMM, gathered A rows)
//   Y:      out += coef * (h@w2^T)        (grouped GEMM, atomicAdd scatter)
// ws layout (bytes):
//   [0,1024)            counts[8]            (zeroed each call)
//   [1024, +256K)       list_idx[8][8192]
//   [263168, +256K)     list_w  [8][8192]
//   [1MiB, +32MiB)      x_bf16 [8192][2048]
//   [36MiB, +129MiB)    h_bf16 [16512][4096]  (16384 slots + 128 pad slack)
// total ~165 MiB
// ---------------------------------------------------------------------------

constexpr int kTokens  = 8192;
constexpr int kHidden  = 2048;
constexpr int kInter   = 4096;
constexpr int kExperts = 8;

constexpr int BM = 128;
constexpr int BN = 128;
constexpr int BK = 64;
constexpr int MAX_MT = (2 * kTokens) / BM + kExperts;  // 136 worst-case m-tiles

typedef short bf16x8 __attribute__((ext_vector_type(8)));
typedef float f32x4  __attribute__((ext_vector_type(4)));

__device__ __forceinline__ unsigned short f2bf(float f) {
  union { float f; unsigned u; } v; v.f = f;
  unsigned r = v.u + 0x7FFFu + ((v.u >> 16) & 1u);  // RTNE
  return (unsigned short)(r >> 16);
}

// ---------------------------- router ----------------------------
__global__ __launch_bounds__(256) void moe_router(
    const float* __restrict__ x, const float* __restrict__ gate_w,
    unsigned short* __restrict__ xb, int* __restrict__ counts,
    int* __restrict__ list_idx, float* __restrict__ list_w)
{
  const int lane = threadIdx.x & 63;
  const int wave = threadIdx.x >> 6;
  const int t = blockIdx.x * 4 + wave;

  float acc[kExperts];
#pragma unroll
  for (int e = 0; e < kExperts; ++e) acc[e] = 0.f;

  const float4* xrow = reinterpret_cast<const float4*>(x + (size_t)t * kHidden);
#pragma unroll
  for (int j = 0; j < 8; ++j) {
    float4 xv = xrow[j * 64 + lane];
    uint2 pk;
    pk.x = (unsigned)f2bf(xv.x) | ((unsigned)f2bf(xv.y) << 16);
    pk.y = (unsigned)f2bf(xv.z) | ((unsigned)f2bf(xv.w) << 16);
    *reinterpret_cast<uint2*>(xb + (size_t)t * kHidden + j * 256 + lane * 4) = pk;
#pragma unroll
    for (int e = 0; e < kExperts; ++e) {
      float4 gv = reinterpret_cast<const float4*>(gate_w + (size_t)e * kHidden)[j * 64 + lane];
      acc[e] += xv.x * gv.x + xv.y * gv.y + xv.z * gv.z + xv.w * gv.w;
    }
  }
#pragma unroll
  for (int e = 0; e < kExperts; ++e) {
#pragma unroll
    for (int m = 32; m >= 1; m >>= 1) acc[e] += __shfl_xor(acc[e], m);
  }
  if (lane == 0) {
    float mx = acc[0];
#pragma unroll
    for (int e = 1; e < kExperts; ++e) mx = fmaxf(mx, acc[e]);
    float p[kExperts]; float s = 0.f;
#pragma unroll
    for (int e = 0; e < kExperts; ++e) { p[e] = __expf(acc[e] - mx); s += p[e]; }
    float inv = 1.f / s;
    // top-1 (ties -> lowest index, matches jax top_k)
    int i1 = 0; float v1 = p[0];
#pragma unroll
    for (int e = 1; e < kExperts; ++e) if (p[e] > v1) { v1 = p[e]; i1 = e; }
    // top-2
    int i2 = (i1 == 0) ? 1 : 0; float v2 = p[i2];
#pragma unroll
    for (int e = 0; e < kExperts; ++e) {
      if (e == i1 || e == i2) continue;
      if (p[e] > v2) { v2 = p[e]; i2 = e; }
    }
    int s1 = atomicAdd(&counts[i1], 1);
    list_idx[i1 * kTokens + s1] = t;
    list_w [i1 * kTokens + s1] = v1 * inv;
    int s2 = atomicAdd(&counts[i2], 1);
    list_idx[i2 * kTokens + s2] = t;
    list_w [i2 * kTokens + s2] = v2 * inv;
  }
}

// ------------------- tile mapping helper (device) -------------------
// maps mt -> (expert e, local tile lm, slot base sb, expert count ne)
// returns false if mt beyond total tiles.
__device__ __forceinline__ bool map_tile(const int* __restrict__ counts, int mt,
                                         int& e, int& lm, int& sb, int& ne)
{
  int tb = 0; sb = 0;
  for (e = 0; e < kExperts; ++e) {
    ne = counts[e];
    int tiles = (ne + BM - 1) / BM;
    if (mt < tb + tiles) { lm = mt - tb; return true; }
    tb += tiles; sb += ne;
  }
  return false;
}

// ---------------------------- GU GEMM ----------------------------
__global__ __launch_bounds__(256, 2) void moe_gu(
    const unsigned short* __restrict__ xb,
    const float* __restrict__ w1, const float* __restrict__ w3,
    const int* __restrict__ counts, const int* __restrict__ list_idx,
    unsigned short* __restrict__ hbuf)
{
  __shared__ unsigned short As [BM * BK];
  __shared__ unsigned short B1s[BN * BK];
  __shared__ unsigned short B3s[BN * BK];
  __shared__ int toks[BM];

  const int tid = threadIdx.x;
  const int nt  = blockIdx.x / MAX_MT;   // consecutive blocks share B panel
  const int mt  = blockIdx.x % MAX_MT;

  int e, lm, sb, ne;
  if (!map_tile(counts, mt, e, lm, sb, ne)) return;
  const int row0 = lm * BM;

  if (tid < BM) {
    int lr = row0 + tid;
    toks[tid] = list_idx[e * kTokens + ((lr < ne) ? lr : 0)];
  }
  __syncthreads();

  const unsigned short* aptr[4];
#pragma unroll
  for (int i = 0; i < 4; ++i) {
    int chunk = i * 256 + tid;
    int r = chunk >> 3, c8 = chunk & 7;
    aptr[i] = xb + (size_t)toks[r] * kHidden + c8 * 8;
  }

  const float* w1e = w1 + (size_t)e * kInter * kHidden;
  const float* w3e = w3 + (size_t)e * kInter * kHidden;

  f32x4 accG[4][4], accU[4][4];
  const f32x4 zero = {0.f, 0.f, 0.f, 0.f};
#pragma unroll
  for (int m = 0; m < 4; ++m)
#pragma unroll
    for (int n = 0; n < 4; ++n) { accG[m][n] = zero; accU[m][n] = zero; }

  const int lane = tid & 63;
  const int wr = (tid >> 6) >> 1;
  const int wc = (tid >> 6) & 1;

  for (int k0 = 0; k0 < kHidden; k0 += BK) {
    // stage A (already bf16): gathered token rows
#pragma unroll
    for (int i = 0; i < 4; ++i) {
      int chunk = i * 256 + tid;
      uint4 v = *reinterpret_cast<const uint4*>(aptr[i] + k0);
      *reinterpret_cast<uint4*>(&As[chunk * 8]) = v;
    }
    // stage B1/B3: fp32 -> bf16 on the fly
#pragma unroll
    for (int i = 0; i < 8; ++i) {
      int c = i * 256 + tid;
      int rowB = c >> 4, c16 = c & 15;
      size_t off = ((size_t)(nt * BN + rowB)) * kHidden + k0 + c16 * 4;
      float4 v1 = *reinterpret_cast<const float4*>(w1e + off);
      float4 v3 = *reinterpret_cast<const float4*>(w3e + off);
      uint2 p1, p3;
      p1.x = (unsigned)f2bf(v1.x) | ((unsigned)f2bf(v1.y) << 16);
      p1.y = (unsigned)f2bf(v1.z) | ((unsigned)f2bf(v1.w) << 16);
      p3.x = (unsigned)f2bf(v3.x) | ((unsigned)f2bf(v3.y) << 16);
      p3.y = (unsigned)f2bf(v3.z) | ((unsigned)f2bf(v3.w) << 16);
      *reinterpret_cast<uint2*>(&B1s[rowB * BK + c16 * 4]) = p1;
      *reinterpret_cast<uint2*>(&B3s[rowB * BK + c16 * 4]) = p3;
    }
    __syncthreads();
#pragma unroll
    for (int kk = 0; kk < 2; ++kk) {
      const int klo = kk * 32 + (lane >> 4) * 8;
      bf16x8 a[4], b1v[4], b3v[4];
#pragma unroll
      for (int m = 0; m < 4; ++m)
        a[m] = *reinterpret_cast<const bf16x8*>(&As[(wr * 64 + m * 16 + (lane & 15)) * BK + klo]);
#pragma unroll
      for (int n = 0; n < 4; ++n) {
        b1v[n] = *reinterpret_cast<const bf16x8*>(&B1s[(wc * 64 + n * 16 + (lane & 15)) * BK + klo]);
        b3v[n] = *reinterpret_cast<const bf16x8*>(&B3s[(wc * 64 + n * 16 + (lane & 15)) * BK + klo]);
      }
#pragma unroll
      for (int m = 0; m < 4; ++m)
#pragma unroll
        for (int n = 0; n < 4; ++n) {
          accG[m][n] = __builtin_amdgcn_mfma_f32_16x16x32_bf16(a[m], b1v[n], accG[m][n], 0, 0, 0);
          accU[m][n] = __builtin_amdgcn_mfma_f32_16x16x32_bf16(a[m], b3v[n], accU[m][n], 0, 0, 0);
        }
    }
    __syncthreads();
  }

  // epilogue: h = silu(g)*u, packed slot layout
#pragma unroll
  for (int m = 0; m < 4; ++m) {
#pragma unroll
    for (int r = 0; r < 4; ++r) {
      int rloc = wr * 64 + m * 16 + ((lane >> 4) * 4) + r;
      int lrow = row0 + rloc;
      if (lrow < ne) {
        size_t base = (size_t)(sb + lrow) * kInter + (size_t)nt * BN + wc * 64 + (lane & 15);
#pragma unroll
        for (int n = 0; n < 4; ++n) {
          float g = accG[m][n][r];
          float u = accU[m][n][r];
          float hv = (g / (1.f + __expf(-g))) * u;
          hbuf[base + n * 16] = f2bf(hv);
        }
      }
    }
  }
}

// ---------------------------- Y GEMM ----------------------------
__global__ __launch_bounds__(256, 2) void moe_y(
    const unsigned short* __restrict__ hbuf,
    const float* __restrict__ w2,
    const int* __restrict__ counts, const int* __restrict__ list_idx,
    const float* __restrict__ list_w,
    float* __restrict__ out)
{
  __shared__ unsigned short As[BM * BK];
  __shared__ unsigned short Bs[BN * BK];
  __shared__ int   toks[BM];
  __shared__ float cofs[BM];

  const int tid = threadIdx.x;
  const int nt  = blockIdx.x / MAX_MT;
  const int mt  = blockIdx.x % MAX_MT;

  int e, lm, sb, ne;
  if (!map_tile(counts, mt, e, lm, sb, ne)) return;
  const int row0 = lm * BM;

  if (tid < BM) {
    int lr = row0 + tid;
    bool v = lr < ne;
    toks[tid] = v ? list_idx[e * kTokens + lr] : 0;
    cofs[tid] = v ? list_w [e * kTokens + lr] : 0.f;
  }
  __syncthreads();

  const float* w2e = w2 + (size_t)e * kHidden * kInter;
  const unsigned short* arow = hbuf + (size_t)(sb + row0) * kInter;

  f32x4 acc[4][4];
  const f32x4 zero = {0.f, 0.f, 0.f, 0.f};
#pragma unroll
  for (int m = 0; m < 4; ++m)
#pragma unroll
    for (int n = 0; n < 4; ++n) acc[m][n] = zero;

  const int lane = tid & 63;
  const int wr = (tid >> 6) >> 1;
  const int wc = (tid >> 6) & 1;

  for (int k0 = 0; k0 < kInter; k0 += BK) {
    // stage A from h (bf16, contiguous slots)
#pragma unroll
    for (int i = 0; i < 4; ++i) {
      int chunk = i * 256 + tid;
      int r = chunk >> 3, c8 = chunk & 7;
      uint4 v = *reinterpret_cast<const uint4*>(arow + (size_t)r * kInter + k0 + c8 * 8);
      *reinterpret_cast<uint4*>(&As[chunk * 8]) = v;
    }
    // stage B (w2 fp32 -> bf16)
#pragma unroll
    for (int i = 0; i < 8; ++i) {
      int c = i * 256 + tid;
      int rowB = c >> 4, c16 = c & 15;
      size_t off = ((size_t)(nt * BN + rowB)) * kInter + k0 + c16 * 4;
      float4 v2 = *reinterpret_cast<const float4*>(w2e + off);
      uint2 p2;
      p2.x = (unsigned)f2bf(v2.x) | ((unsigned)f2bf(v2.y) << 16);
      p2.y = (unsigned)f2bf(v2.z) | ((unsigned)f2bf(v2.w) << 16);
      *reinterpret_cast<uint2*>(&Bs[rowB * BK + c16 * 4]) = p2;
    }
    __syncthreads();
#pragma unroll
    for (int kk = 0; kk < 2; ++kk) {
      const int klo = kk * 32 + (lane >> 4) * 8;
      bf16x8 a[4], b[4];
#pragma unroll
      for (int m = 0; m < 4; ++m)
        a[m] = *reinterpret_cast<const bf16x8*>(&As[(wr * 64 + m * 16 + (lane & 15)) * BK + klo]);
#pragma unroll
      for (int n = 0; n < 4; ++n)
        b[n] = *reinterpret_cast<const bf16x8*>(&Bs[(wc * 64 + n * 16 + (lane & 15)) * BK + klo]);
#pragma unroll
      for (int m = 0; m < 4; ++m)
#pragma unroll
        for (int n = 0; n < 4; ++n)
          acc[m][n] = __builtin_amdgcn_mfma_f32_16x16x32_bf16(a[m], b[n], acc[m][n], 0, 0, 0);
    }
    __syncthreads();
  }

  // epilogue: out[token] += coef * y  (each element gets exactly 2 adds)
#pragma unroll
  for (int m = 0; m < 4; ++m) {
#pragma unroll
    for (int r = 0; r < 4; ++r) {
      int rloc = wr * 64 + m * 16 + ((lane >> 4) * 4) + r;
      if (row0 + rloc < ne) {
        float cf = cofs[rloc];
        size_t obase = (size_t)toks[rloc] * kHidden + (size_t)nt * BN + wc * 64 + (lane & 15);
#pragma unroll
        for (int n = 0; n < 4; ++n)
          atomicAdd(&out[obase + n * 16], cf * acc[m][n][r]);
      }
    }
  }
}

// ---------------------------- host ----------------------------
extern "C" void kernel_launch(void* const* d_in, const int* in_sizes, int n_in,
                              void* d_out, int out_size, void* d_ws, size_t ws_size,
                              hipStream_t stream)
{
  const float* x      = (const float*)d_in[0];
  const float* gate_w = (const float*)d_in[1];
  const float* w1     = (const float*)d_in[2];
  const float* w2     = (const float*)d_in[3];
  const float* w3     = (const float*)d_in[4];
  float* out = (float*)d_out;

  char* ws = (char*)d_ws;
  int*   counts   = (int*)(ws);
  int*   list_idx = (int*)(ws + 1024);
  float* list_w   = (float*)(ws + 1024 + kExperts * kTokens * 4);
  unsigned short* xb   = (unsigned short*)(ws + (1u << 20));
  unsigned short* hbuf = (unsigned short*)(ws + (size_t)36 * (1u << 20));

  hipMemsetAsync(counts, 0, 1024, stream);
  hipMemsetAsync(out, 0, (size_t)kTokens * kHidden * sizeof(float), stream);

  moe_router<<<kTokens / 4, 256, 0, stream>>>(x, gate_w, xb, counts, list_idx, list_w);
  moe_gu<<<(kInter / BN) * MAX_MT, 256, 0, stream>>>(xb, w1, w3, counts, list_idx, hbuf);
  moe_y <<<(kHidden / BN) * MAX_MT, 256, 0, stream>>>(hbuf, w2, counts, list_idx, list_w, out);
}

// Round 2
// 1497.508 us; speedup vs baseline: 2.7040x; 2.7040x over previous
//
#include <hip/hip_runtime.h>
#include <stdint.h>
#include <stddef.h>

// ---------------------------------------------------------------------------
// Sparse top-2 MoE, bf16 MFMA, fp32 accumulate.
//   convert: w1/w3/w2 fp32 -> bf16, tile-panel layout [e][p][q][128x64],
//            XOR-swizzled (chunk cs holds logical col cs^(row&7)) so
//            global_load_lds stages linearly and ds_read_b128 is conflict-free
//   router:  logits -> softmax -> top2 -> per-expert compact lists (+x->bf16)
//   GU:      h = silu(x@w1^T) * (x@w3^T)
//   Y:       out += coef * (h@w2^T)
// ws layout (MiB): [0,1) lists | [1,33) xb | [33,161) w1b (later w2b)
//                  [161,289) w3b | [289,418) hbuf
// ---------------------------------------------------------------------------

constexpr int kTokens  = 8192;
constexpr int kHidden  = 2048;
constexpr int kInter   = 4096;
constexpr int kExperts = 8;

constexpr int BM = 128;
constexpr int BN = 128;
constexpr int BK = 64;
constexpr int MAX_MT = (2 * kTokens) / BM + kExperts;  // 136 worst-case m-tiles

typedef short bf16x8 __attribute__((ext_vector_type(8)));
typedef float f32x4  __attribute__((ext_vector_type(4)));
typedef unsigned int u32;

__device__ __forceinline__ unsigned short f2bf(float f) {
  union { float f; unsigned u; } v; v.f = f;
  unsigned r = v.u + 0x7FFFu + ((v.u >> 16) & 1u);  // RTNE
  return (unsigned short)(r >> 16);
}

// async global -> LDS, 16B per lane. LDS dest = wave-uniform base + lane*16.
__device__ __forceinline__ void gload16(const void* g, void* l) {
  __builtin_amdgcn_global_load_lds(
      (const __attribute__((address_space(1))) u32*)g,
      (__attribute__((address_space(3))) u32*)l, 16, 0, 0);
}

// ---------------------------- weight convert ----------------------------
// dst chunk g (16B = 8 bf16): block = g>>10 -> (e,p,q); l = g&1023 -> (r,cs).
// chunk holds source row (e*P+p)*128+r, cols q*64 + (cs^(r&7))*8 .. +8.
__global__ __launch_bounds__(256) void convert_w(
    const float* __restrict__ src, unsigned short* __restrict__ dst,
    int lp, int lq, int K, long nchunks)
{
  long stride = (long)gridDim.x * blockDim.x;
  for (long g = blockIdx.x * (long)blockDim.x + threadIdx.x; g < nchunks; g += stride) {
    int  l   = (int)(g & 1023);
    long blk = g >> 10;
    int  q   = (int)(blk & ((1 << lq) - 1));
    long ep  = blk >> lq;
    int  p   = (int)(ep & ((1 << lp) - 1));
    int  e   = (int)(ep >> lp);
    int r = l >> 3, cs = l & 7, c = cs ^ (r & 7);
    size_t soff = (((size_t)(e << lp) + p) * 128 + r) * (size_t)K + (size_t)q * 64 + c * 8;
    float4 v0 = *reinterpret_cast<const float4*>(src + soff);
    float4 v1 = *reinterpret_cast<const float4*>(src + soff + 4);
    uint4 o;
    o.x = (u32)f2bf(v0.x) | ((u32)f2bf(v0.y) << 16);
    o.y = (u32)f2bf(v0.z) | ((u32)f2bf(v0.w) << 16);
    o.z = (u32)f2bf(v1.x) | ((u32)f2bf(v1.y) << 16);
    o.w = (u32)f2bf(v1.z) | ((u32)f2bf(v1.w) << 16);
    *reinterpret_cast<uint4*>(dst + g * 8) = o;
  }
}

// ---------------------------- router ----------------------------
__global__ __launch_bounds__(256) void moe_router(
    const float* __restrict__ x, const float* __restrict__ gate_w,
    unsigned short* __restrict__ xb, int* __restrict__ counts,
    int* __restrict__ list_idx, float* __restrict__ list_w)
{
  const int lane = threadIdx.x & 63;
  const int wave = threadIdx.x >> 6;
  const int t = blockIdx.x * 4 + wave;

  float acc[kExperts];
#pragma unroll
  for (int e = 0; e < kExperts; ++e) acc[e] = 0.f;

  const float4* xrow = reinterpret_cast<const float4*>(x + (size_t)t * kHidden);
#pragma unroll
  for (int j = 0; j < 8; ++j) {
    float4 xv = xrow[j * 64 + lane];
    uint2 pk;
    pk.x = (u32)f2bf(xv.x) | ((u32)f2bf(xv.y) << 16);
    pk.y = (u32)f2bf(xv.z) | ((u32)f2bf(xv.w) << 16);
    *reinterpret_cast<uint2*>(xb + (size_t)t * kHidden + j * 256 + lane * 4) = pk;
#pragma unroll
    for (int e = 0; e < kExperts; ++e) {
      float4 gv = reinterpret_cast<const float4*>(gate_w + (size_t)e * kHidden)[j * 64 + lane];
      acc[e] += xv.x * gv.x + xv.y * gv.y + xv.z * gv.z + xv.w * gv.w;
    }
  }
#pragma unroll
  for (int e = 0; e < kExperts; ++e) {
#pragma unroll
    for (int m = 32; m >= 1; m >>= 1) acc[e] += __shfl_xor(acc[e], m);
  }
  if (lane == 0) {
    float mx = acc[0];
#pragma unroll
    for (int e = 1; e < kExperts; ++e) mx = fmaxf(mx, acc[e]);
    float p[kExperts]; float s = 0.f;
#pragma unroll
    for (int e = 0; e < kExperts; ++e) { p[e] = __expf(acc[e] - mx); s += p[e]; }
    float inv = 1.f / s;
    int i1 = 0; float v1 = p[0];
#pragma unroll
    for (int e = 1; e < kExperts; ++e) if (p[e] > v1) { v1 = p[e]; i1 = e; }
    int i2 = (i1 == 0) ? 1 : 0; float v2 = p[i2];
#pragma unroll
    for (int e = 0; e < kExperts; ++e) {
      if (e == i1 || e == i2) continue;
      if (p[e] > v2) { v2 = p[e]; i2 = e; }
    }
    int s1 = atomicAdd(&counts[i1], 1);
    list_idx[i1 * kTokens + s1] = t;
    list_w [i1 * kTokens + s1] = v1 * inv;
    int s2 = atomicAdd(&counts[i2], 1);
    list_idx[i2 * kTokens + s2] = t;
    list_w [i2 * kTokens + s2] = v2 * inv;
  }
}

// ------------------- tile mapping helper -------------------
__device__ __forceinline__ bool map_tile(const int* __restrict__ counts, int mt,
                                         int& e, int& lm, int& sb, int& ne)
{
  int tb = 0; sb = 0;
  for (e = 0; e < kExperts; ++e) {
    ne = counts[e];
    int tiles = (ne + BM - 1) / BM;
    if (mt < tb + tiles) { lm = mt - tb; return true; }
    tb += tiles; sb += ne;
  }
  return false;
}

// ---------------------------- GU GEMM (bf16 weights, global_load_lds) -------
__global__ __launch_bounds__(256, 2) void moe_gu(
    const unsigned short* __restrict__ xb,
    const unsigned short* __restrict__ w1b, const unsigned short* __restrict__ w3b,
    const int* __restrict__ counts, const int* __restrict__ list_idx,
    unsigned short* __restrict__ hbuf)
{
  __shared__ unsigned short As [BM * BK];
  __shared__ unsigned short B1s[BN * BK];
  __shared__ unsigned short B3s[BN * BK];
  __shared__ int toks[BM];

  const int tid = threadIdx.x;
  const int nt  = blockIdx.x / MAX_MT;
  const int mt  = blockIdx.x % MAX_MT;

  int e, lm, sb, ne;
  if (!map_tile(counts, mt, e, lm, sb, ne)) return;
  const int row0 = lm * BM;

  if (tid < BM) {
    int lr = row0 + tid;
    toks[tid] = list_idx[e * kTokens + ((lr < ne) ? lr : 0)];
  }
  __syncthreads();

  const int lane = tid & 63;
  const int w = tid >> 6;
  const int wr = w >> 1, wc = w & 1;

  // staging sources: A gathered+swizzled per lane; B linear (pre-swizzled buf)
  const unsigned short* srcA[4];
  const unsigned short* srcB1[4];
  const unsigned short* srcB3[4];
  const size_t bbase = ((size_t)(e * (kInter / BN) + nt) * (kHidden / BK)) * 1024;
#pragma unroll
  for (int i = 0; i < 4; ++i) {
    int l = (w * 4 + i) * 64 + lane;
    int r = l >> 3, cs = l & 7, c = cs ^ (r & 7);
    srcA[i]  = xb  + (size_t)toks[r] * kHidden + c * 8;
    srcB1[i] = w1b + (bbase + l) * 8;
    srcB3[i] = w3b + (bbase + l) * 8;
  }

  f32x4 accG[4][4], accU[4][4];
  const f32x4 zero = {0.f, 0.f, 0.f, 0.f};
#pragma unroll
  for (int m = 0; m < 4; ++m)
#pragma unroll
    for (int n = 0; n < 4; ++n) { accG[m][n] = zero; accU[m][n] = zero; }

  for (int ks = 0; ks < kHidden / BK; ++ks) {
#pragma unroll
    for (int i = 0; i < 4; ++i) {
      gload16(srcA[i]  + ks * BK,            &As [(w * 4 + i) * 512]);
      gload16(srcB1[i] + (size_t)ks * 8192,  &B1s[(w * 4 + i) * 512]);
      gload16(srcB3[i] + (size_t)ks * 8192,  &B3s[(w * 4 + i) * 512]);
    }
    __syncthreads();   // implicit vmcnt(0): staged tile visible
#pragma unroll
    for (int kk = 0; kk < 2; ++kk) {
      const int cq = kk * 4 + (lane >> 4);
      bf16x8 a[4], b1v[4], b3v[4];
#pragma unroll
      for (int m = 0; m < 4; ++m) {
        int row = wr * 64 + m * 16 + (lane & 15);
        a[m] = *reinterpret_cast<const bf16x8*>(&As[row * 64 + ((cq ^ (row & 7)) << 3)]);
      }
#pragma unroll
      for (int n = 0; n < 4; ++n) {
        int row = wc * 64 + n * 16 + (lane & 15);
        b1v[n] = *reinterpret_cast<const bf16x8*>(&B1s[row * 64 + ((cq ^ (row & 7)) << 3)]);
        b3v[n] = *reinterpret_cast<const bf16x8*>(&B3s[row * 64 + ((cq ^ (row & 7)) << 3)]);
      }
#pragma unroll
      for (int m = 0; m < 4; ++m)
#pragma unroll
        for (int n = 0; n < 4; ++n) {
          accG[m][n] = __builtin_amdgcn_mfma_f32_16x16x32_bf16(a[m], b1v[n], accG[m][n], 0, 0, 0);
          accU[m][n] = __builtin_amdgcn_mfma_f32_16x16x32_bf16(a[m], b3v[n], accU[m][n], 0, 0, 0);
        }
    }
    __syncthreads();
  }

#pragma unroll
  for (int m = 0; m < 4; ++m) {
#pragma unroll
    for (int r = 0; r < 4; ++r) {
      int rloc = wr * 64 + m * 16 + ((lane >> 4) * 4) + r;
      int lrow = row0 + rloc;
      if (lrow < ne) {
        size_t base = (size_t)(sb + lrow) * kInter + (size_t)nt * BN + wc * 64 + (lane & 15);
#pragma unroll
        for (int n = 0; n < 4; ++n) {
          float g = accG[m][n][r];
          float u = accU[m][n][r];
          float hv = (g / (1.f + __expf(-g))) * u;
          hbuf[base + n * 16] = f2bf(hv);
        }
      }
    }
  }
}

// ---------------------------- Y GEMM ----------------------------
__global__ __launch_bounds__(256, 3) void moe_y(
    const unsigned short* __restrict__ hbuf,
    const unsigned short* __restrict__ w2b,
    const int* __restrict__ counts, const int* __restrict__ list_idx,
    const float* __restrict__ list_w,
    float* __restrict__ out)
{
  __shared__ unsigned short As[BM * BK];
  __shared__ unsigned short Bs[BN * BK];
  __shared__ int   toks[BM];
  __shared__ float cofs[BM];

  const int tid = threadIdx.x;
  const int nt  = blockIdx.x / MAX_MT;
  const int mt  = blockIdx.x % MAX_MT;

  int e, lm, sb, ne;
  if (!map_tile(counts, mt, e, lm, sb, ne)) return;
  const int row0 = lm * BM;

  if (tid < BM) {
    int lr = row0 + tid;
    bool v = lr < ne;
    toks[tid] = v ? list_idx[e * kTokens + lr] : 0;
    cofs[tid] = v ? list_w [e * kTokens + lr] : 0.f;
  }
  __syncthreads();

  const int lane = tid & 63;
  const int w = tid >> 6;
  const int wr = w >> 1, wc = w & 1;

  const unsigned short* srcA[4];
  const unsigned short* srcB2[4];
  const size_t bbase = ((size_t)(e * (kHidden / BN) + nt) * (kInter / BK)) * 1024;
#pragma unroll
  for (int i = 0; i < 4; ++i) {
    int l = (w * 4 + i) * 64 + lane;
    int r = l >> 3, cs = l & 7, c = cs ^ (r & 7);
    srcA[i]  = hbuf + (size_t)(sb + row0 + r) * kInter + c * 8;
    srcB2[i] = w2b  + (bbase + l) * 8;
  }

  f32x4 acc[4][4];
  const f32x4 zero = {0.f, 0.f, 0.f, 0.f};
#pragma unroll
  for (int m = 0; m < 4; ++m)
#pragma unroll
    for (int n = 0; n < 4; ++n) acc[m][n] = zero;

  for (int ks = 0; ks < kInter / BK; ++ks) {
#pragma unroll
    for (int i = 0; i < 4; ++i) {
      gload16(srcA[i]  + ks * BK,           &As[(w * 4 + i) * 512]);
      gload16(srcB2[i] + (size_t)ks * 8192, &Bs[(w * 4 + i) * 512]);
    }
    __syncthreads();
#pragma unroll
    for (int kk = 0; kk < 2; ++kk) {
      const int cq = kk * 4 + (lane >> 4);
      bf16x8 a[4], b[4];
#pragma unroll
      for (int m = 0; m < 4; ++m) {
        int row = wr * 64 + m * 16 + (lane & 15);
        a[m] = *reinterpret_cast<const bf16x8*>(&As[row * 64 + ((cq ^ (row & 7)) << 3)]);
      }
#pragma unroll
      for (int n = 0; n < 4; ++n) {
        int row = wc * 64 + n * 16 + (lane & 15);
        b[n] = *reinterpret_cast<const bf16x8*>(&Bs[row * 64 + ((cq ^ (row & 7)) << 3)]);
      }
#pragma unroll
      for (int m = 0; m < 4; ++m)
#pragma unroll
        for (int n = 0; n < 4; ++n)
          acc[m][n] = __builtin_amdgcn_mfma_f32_16x16x32_bf16(a[m], b[n], acc[m][n], 0, 0, 0);
    }
    __syncthreads();
  }

#pragma unroll
  for (int m = 0; m < 4; ++m) {
#pragma unroll
    for (int r = 0; r < 4; ++r) {
      int rloc = wr * 64 + m * 16 + ((lane >> 4) * 4) + r;
      if (row0 + rloc < ne) {
        float cf = cofs[rloc];
        size_t obase = (size_t)toks[rloc] * kHidden + (size_t)nt * BN + wc * 64 + (lane & 15);
#pragma unroll
        for (int n = 0; n < 4; ++n)
          atomicAdd(&out[obase + n * 16], cf * acc[m][n][r]);
      }
    }
  }
}

// ===================== fallback (fp32 on-the-fly) — round-1 path ============
__global__ __launch_bounds__(256, 2) void moe_gu_f32(
    const unsigned short* __restrict__ xb,
    const float* __restrict__ w1, const float* __restrict__ w3,
    const int* __restrict__ counts, const int* __restrict__ list_idx,
    unsigned short* __restrict__ hbuf)
{
  __shared__ unsigned short As [BM * BK];
  __shared__ unsigned short B1s[BN * BK];
  __shared__ unsigned short B3s[BN * BK];
  __shared__ int toks[BM];

  const int tid = threadIdx.x;
  const int nt  = blockIdx.x / MAX_MT;
  const int mt  = blockIdx.x % MAX_MT;

  int e, lm, sb, ne;
  if (!map_tile(counts, mt, e, lm, sb, ne)) return;
  const int row0 = lm * BM;

  if (tid < BM) {
    int lr = row0 + tid;
    toks[tid] = list_idx[e * kTokens + ((lr < ne) ? lr : 0)];
  }
  __syncthreads();

  const unsigned short* aptr[4];
#pragma unroll
  for (int i = 0; i < 4; ++i) {
    int chunk = i * 256 + tid;
    int r = chunk >> 3, c8 = chunk & 7;
    aptr[i] = xb + (size_t)toks[r] * kHidden + c8 * 8;
  }
  const float* w1e = w1 + (size_t)e * kInter * kHidden;
  const float* w3e = w3 + (size_t)e * kInter * kHidden;

  f32x4 accG[4][4], accU[4][4];
  const f32x4 zero = {0.f, 0.f, 0.f, 0.f};
#pragma unroll
  for (int m = 0; m < 4; ++m)
#pragma unroll
    for (int n = 0; n < 4; ++n) { accG[m][n] = zero; accU[m][n] = zero; }

  const int lane = tid & 63;
  const int wr = (tid >> 6) >> 1;
  const int wc = (tid >> 6) & 1;

  for (int k0 = 0; k0 < kHidden; k0 += BK) {
#pragma unroll
    for (int i = 0; i < 4; ++i) {
      int chunk = i * 256 + tid;
      uint4 v = *reinterpret_cast<const uint4*>(aptr[i] + k0);
      *reinterpret_cast<uint4*>(&As[chunk * 8]) = v;
    }
#pragma unroll
    for (int i = 0; i < 8; ++i) {
      int c = i * 256 + tid;
      int rowB = c >> 4, c16 = c & 15;
      size_t off = ((size_t)(nt * BN + rowB)) * kHidden + k0 + c16 * 4;
      float4 v1 = *reinterpret_cast<const float4*>(w1e + off);
      float4 v3 = *reinterpret_cast<const float4*>(w3e + off);
      uint2 p1, p3;
      p1.x = (u32)f2bf(v1.x) | ((u32)f2bf(v1.y) << 16);
      p1.y = (u32)f2bf(v1.z) | ((u32)f2bf(v1.w) << 16);
      p3.x = (u32)f2bf(v3.x) | ((u32)f2bf(v3.y) << 16);
      p3.y = (u32)f2bf(v3.z) | ((u32)f2bf(v3.w) << 16);
      *reinterpret_cast<uint2*>(&B1s[rowB * BK + c16 * 4]) = p1;
      *reinterpret_cast<uint2*>(&B3s[rowB * BK + c16 * 4]) = p3;
    }
    __syncthreads();
#pragma unroll
    for (int kk = 0; kk < 2; ++kk) {
      const int klo = kk * 32 + (lane >> 4) * 8;
      bf16x8 a[4], b1v[4], b3v[4];
#pragma unroll
      for (int m = 0; m < 4; ++m)
        a[m] = *reinterpret_cast<const bf16x8*>(&As[(wr * 64 + m * 16 + (lane & 15)) * BK + klo]);
#pragma unroll
      for (int n = 0; n < 4; ++n) {
        b1v[n] = *reinterpret_cast<const bf16x8*>(&B1s[(wc * 64 + n * 16 + (lane & 15)) * BK + klo]);
        b3v[n] = *reinterpret_cast<const bf16x8*>(&B3s[(wc * 64 + n * 16 + (lane & 15)) * BK + klo]);
      }
#pragma unroll
      for (int m = 0; m < 4; ++m)
#pragma unroll
        for (int n = 0; n < 4; ++n) {
          accG[m][n] = __builtin_amdgcn_mfma_f32_16x16x32_bf16(a[m], b1v[n], accG[m][n], 0, 0, 0);
          accU[m][n] = __builtin_amdgcn_mfma_f32_16x16x32_bf16(a[m], b3v[n], accU[m][n], 0, 0, 0);
        }
    }
    __syncthreads();
  }
#pragma unroll
  for (int m = 0; m < 4; ++m) {
#pragma unroll
    for (int r = 0; r < 4; ++r) {
      int rloc = wr * 64 + m * 16 + ((lane >> 4) * 4) + r;
      int lrow = row0 + rloc;
      if (lrow < ne) {
        size_t base = (size_t)(sb + lrow) * kInter + (size_t)nt * BN + wc * 64 + (lane & 15);
#pragma unroll
        for (int n = 0; n < 4; ++n) {
          float g = accG[m][n][r];
          float u = accU[m][n][r];
          hbuf[base + n * 16] = f2bf((g / (1.f + __expf(-g))) * u);
        }
      }
    }
  }
}

__global__ __launch_bounds__(256, 2) void moe_y_f32(
    const unsigned short* __restrict__ hbuf,
    const float* __restrict__ w2,
    const int* __restrict__ counts, const int* __restrict__ list_idx,
    const float* __restrict__ list_w,
    float* __restrict__ out)
{
  __shared__ unsigned short As[BM * BK];
  __shared__ unsigned short Bs[BN * BK];
  __shared__ int   toks[BM];
  __shared__ float cofs[BM];

  const int tid = threadIdx.x;
  const int nt  = blockIdx.x / MAX_MT;
  const int mt  = blockIdx.x % MAX_MT;

  int e, lm, sb, ne;
  if (!map_tile(counts, mt, e, lm, sb, ne)) return;
  const int row0 = lm * BM;

  if (tid < BM) {
    int lr = row0 + tid;
    bool v = lr < ne;
    toks[tid] = v ? list_idx[e * kTokens + lr] : 0;
    cofs[tid] = v ? list_w [e * kTokens + lr] : 0.f;
  }
  __syncthreads();

  const float* w2e = w2 + (size_t)e * kHidden * kInter;
  const unsigned short* arow = hbuf + (size_t)(sb + row0) * kInter;

  f32x4 acc[4][4];
  const f32x4 zero = {0.f, 0.f, 0.f, 0.f};
#pragma unroll
  for (int m = 0; m < 4; ++m)
#pragma unroll
    for (int n = 0; n < 4; ++n) acc[m][n] = zero;

  const int lane = tid & 63;
  const int wr = (tid >> 6) >> 1;
  const int wc = (tid >> 6) & 1;

  for (int k0 = 0; k0 < kInter; k0 += BK) {
#pragma unroll
    for (int i = 0; i < 4; ++i) {
      int chunk = i * 256 + tid;
      int r = chunk >> 3, c8 = chunk & 7;
      uint4 v = *reinterpret_cast<const uint4*>(arow + (size_t)r * kInter + k0 + c8 * 8);
      *reinterpret_cast<uint4*>(&As[chunk * 8]) = v;
    }
#pragma unroll
    for (int i = 0; i < 8; ++i) {
      int c = i * 256 + tid;
      int rowB = c >> 4, c16 = c & 15;
      size_t off = ((size_t)(nt * BN + rowB)) * kInter + k0 + c16 * 4;
      float4 v2 = *reinterpret_cast<const float4*>(w2e + off);
      uint2 p2;
      p2.x = (u32)f2bf(v2.x) | ((u32)f2bf(v2.y) << 16);
      p2.y = (u32)f2bf(v2.z) | ((u32)f2bf(v2.w) << 16);
      *reinterpret_cast<uint2*>(&Bs[rowB * BK + c16 * 4]) = p2;
    }
    __syncthreads();
#pragma unroll
    for (int kk = 0; kk < 2; ++kk) {
      const int klo = kk * 32 + (lane >> 4) * 8;
      bf16x8 a[4], b[4];
#pragma unroll
      for (int m = 0; m < 4; ++m)
        a[m] = *reinterpret_cast<const bf16x8*>(&As[(wr * 64 + m * 16 + (lane & 15)) * BK + klo]);
#pragma unroll
      for (int n = 0; n < 4; ++n)
        b[n] = *reinterpret_cast<const bf16x8*>(&Bs[(wc * 64 + n * 16 + (lane & 15)) * BK + klo]);
#pragma unroll
      for (int m = 0; m < 4; ++m)
#pragma unroll
        for (int n = 0; n < 4; ++n)
          acc[m][n] = __builtin_amdgcn_mfma_f32_16x16x32_bf16(a[m], b[n], acc[m][n], 0, 0, 0);
    }
    __syncthreads();
  }
#pragma unroll
  for (int m = 0; m < 4; ++m) {
#pragma unroll
    for (int r = 0; r < 4; ++r) {
      int rloc = wr * 64 + m * 16 + ((lane >> 4) * 4) + r;
      if (row0 + rloc < ne) {
        float cf = cofs[rloc];
        size_t obase = (size_t)toks[rloc] * kHidden + (size_t)nt * BN + wc * 64 + (lane & 15);
#pragma unroll
        for (int n = 0; n < 4; ++n)
          atomicAdd(&out[obase + n * 16], cf * acc[m][n][r]);
      }
    }
  }
}

// ---------------------------- host ----------------------------
extern "C" void kernel_launch(void* const* d_in, const int* in_sizes, int n_in,
                              void* d_out, int out_size, void* d_ws, size_t ws_size,
                              hipStream_t stream)
{
  const float* x      = (const float*)d_in[0];
  const float* gate_w = (const float*)d_in[1];
  const float* w1     = (const float*)d_in[2];
  const float* w2     = (const float*)d_in[3];
  const float* w3     = (const float*)d_in[4];
  float* out = (float*)d_out;

  char* ws = (char*)d_ws;
  const size_t MiB = 1ull << 20;
  int*   counts   = (int*)(ws);
  int*   list_idx = (int*)(ws + 1024);
  float* list_w   = (float*)(ws + 1024 + kExperts * kTokens * 4);

  hipMemsetAsync(counts, 0, 1024, stream);
  hipMemsetAsync(out, 0, (size_t)kTokens * kHidden * sizeof(float), stream);

  if (ws_size >= 418 * MiB) {
    unsigned short* xb   = (unsigned short*)(ws + 1 * MiB);
    unsigned short* w1b  = (unsigned short*)(ws + 33 * MiB);
    unsigned short* w3b  = (unsigned short*)(ws + 161 * MiB);
    unsigned short* hbuf = (unsigned short*)(ws + 289 * MiB);
    unsigned short* w2b  = w1b;  // reuse after GU is done with w1b

    const long nch = (long)kExperts * (kInter / BN) * (kHidden / BK) * 1024;  // == w2's too
    convert_w<<<4096, 256, 0, stream>>>(w1, w1b, 5, 5, kHidden, nch);
    convert_w<<<4096, 256, 0, stream>>>(w3, w3b, 5, 5, kHidden, nch);
    moe_router<<<kTokens / 4, 256, 0, stream>>>(x, gate_w, xb, counts, list_idx, list_w);
    moe_gu<<<(kInter / BN) * MAX_MT, 256, 0, stream>>>(xb, w1b, w3b, counts, list_idx, hbuf);
    convert_w<<<4096, 256, 0, stream>>>(w2, w2b, 4, 6, kInter, nch);
    moe_y<<<(kHidden / BN) * MAX_MT, 256, 0, stream>>>(hbuf, w2b, counts, list_idx, list_w, out);
  } else {
    unsigned short* xb   = (unsigned short*)(ws + 1 * MiB);
    unsigned short* hbuf = (unsigned short*)(ws + 36 * MiB);
    moe_router<<<kTokens / 4, 256, 0, stream>>>(x, gate_w, xb, counts, list_idx, list_w);
    moe_gu_f32<<<(kInter / BN) * MAX_MT, 256, 0, stream>>>(xb, w1, w3, counts, list_idx, hbuf);
    moe_y_f32 <<<(kHidden / BN) * MAX_MT, 256, 0, stream>>>(hbuf, w2, counts, list_idx, list_w, out);
  }
}

// Round 3
// 1491.830 us; speedup vs baseline: 2.7143x; 1.0038x over previous
//
#include <hip/hip_runtime.h>
#include <stdint.h>
#include <stddef.h>

// ---------------------------------------------------------------------------
// Sparse top-2 MoE, bf16 MFMA, fp32 accumulate.
//   convert: w1/w3/w2 fp32 -> bf16, tile-panel layout [e][p][q][128x64],
//            XOR-swizzled (chunk cs holds logical col cs^(r&7))
//   router:  logits -> softmax -> top2 -> per-expert compact lists (+x->bf16)
//   GU:      h = silu(x@w1^T) * (x@w3^T)   4-phase counted-vmcnt pipeline
//   Y:       out += coef * (h@w2^T)        (round-2 proven structure)
// ws layout (MiB): [0,1) lists | [1,33) xb | [33,161) w1b (later w2b)
//                  [161,289) w3b | [289,418) hbuf
// ---------------------------------------------------------------------------

constexpr int kTokens  = 8192;
constexpr int kHidden  = 2048;
constexpr int kInter   = 4096;
constexpr int kExperts = 8;

constexpr int BM = 128, BN = 128, BK = 64;          // Y tile
constexpr int MAX_MT = (2 * kTokens) / BM + kExperts;   // 136

constexpr int BM2 = 256, BN2 = 128, BK2 = 64;       // GU tile
constexpr int MAX_MT2 = (2 * kTokens) / BM2 + kExperts; // 72
constexpr int NT2 = kHidden / BK2;                  // 32 K-tiles

typedef short bf16x8 __attribute__((ext_vector_type(8)));
typedef float f32x4  __attribute__((ext_vector_type(4)));
typedef unsigned int u32;

__device__ __forceinline__ unsigned short f2bf(float f) {
  union { float f; unsigned u; } v; v.f = f;
  unsigned r = v.u + 0x7FFFu + ((v.u >> 16) & 1u);  // RTNE
  return (unsigned short)(r >> 16);
}

__device__ __forceinline__ void gload16(const void* g, void* l) {
  __builtin_amdgcn_global_load_lds(
      (const __attribute__((address_space(1))) u32*)g,
      (__attribute__((address_space(3))) u32*)l, 16, 0, 0);
}

// ---------------------------- weight convert ----------------------------
__global__ __launch_bounds__(256) void convert_w(
    const float* __restrict__ src, unsigned short* __restrict__ dst,
    int lp, int lq, int K, long nchunks)
{
  long stride = (long)gridDim.x * blockDim.x;
  for (long g = blockIdx.x * (long)blockDim.x + threadIdx.x; g < nchunks; g += stride) {
    int  l   = (int)(g & 1023);
    long blk = g >> 10;
    int  q   = (int)(blk & ((1 << lq) - 1));
    long ep  = blk >> lq;
    int  p   = (int)(ep & ((1 << lp) - 1));
    int  e   = (int)(ep >> lp);
    int r = l >> 3, cs = l & 7, c = cs ^ (r & 7);
    size_t soff = (((size_t)(e << lp) + p) * 128 + r) * (size_t)K + (size_t)q * 64 + c * 8;
    float4 v0 = *reinterpret_cast<const float4*>(src + soff);
    float4 v1 = *reinterpret_cast<const float4*>(src + soff + 4);
    uint4 o;
    o.x = (u32)f2bf(v0.x) | ((u32)f2bf(v0.y) << 16);
    o.y = (u32)f2bf(v0.z) | ((u32)f2bf(v0.w) << 16);
    o.z = (u32)f2bf(v1.x) | ((u32)f2bf(v1.y) << 16);
    o.w = (u32)f2bf(v1.z) | ((u32)f2bf(v1.w) << 16);
    *reinterpret_cast<uint4*>(dst + g * 8) = o;
  }
}

// ---------------------------- router ----------------------------
__global__ __launch_bounds__(256) void moe_router(
    const float* __restrict__ x, const float* __restrict__ gate_w,
    unsigned short* __restrict__ xb, int* __restrict__ counts,
    int* __restrict__ list_idx, float* __restrict__ list_w)
{
  const int lane = threadIdx.x & 63;
  const int wave = threadIdx.x >> 6;
  const int t = blockIdx.x * 4 + wave;

  float acc[kExperts];
#pragma unroll
  for (int e = 0; e < kExperts; ++e) acc[e] = 0.f;

  const float4* xrow = reinterpret_cast<const float4*>(x + (size_t)t * kHidden);
#pragma unroll
  for (int j = 0; j < 8; ++j) {
    float4 xv = xrow[j * 64 + lane];
    uint2 pk;
    pk.x = (u32)f2bf(xv.x) | ((u32)f2bf(xv.y) << 16);
    pk.y = (u32)f2bf(xv.z) | ((u32)f2bf(xv.w) << 16);
    *reinterpret_cast<uint2*>(xb + (size_t)t * kHidden + j * 256 + lane * 4) = pk;
#pragma unroll
    for (int e = 0; e < kExperts; ++e) {
      float4 gv = reinterpret_cast<const float4*>(gate_w + (size_t)e * kHidden)[j * 64 + lane];
      acc[e] += xv.x * gv.x + xv.y * gv.y + xv.z * gv.z + xv.w * gv.w;
    }
  }
#pragma unroll
  for (int e = 0; e < kExperts; ++e) {
#pragma unroll
    for (int m = 32; m >= 1; m >>= 1) acc[e] += __shfl_xor(acc[e], m);
  }
  if (lane == 0) {
    float mx = acc[0];
#pragma unroll
    for (int e = 1; e < kExperts; ++e) mx = fmaxf(mx, acc[e]);
    float p[kExperts]; float s = 0.f;
#pragma unroll
    for (int e = 0; e < kExperts; ++e) { p[e] = __expf(acc[e] - mx); s += p[e]; }
    float inv = 1.f / s;
    int i1 = 0; float v1 = p[0];
#pragma unroll
    for (int e = 1; e < kExperts; ++e) if (p[e] > v1) { v1 = p[e]; i1 = e; }
    int i2 = (i1 == 0) ? 1 : 0; float v2 = p[i2];
#pragma unroll
    for (int e = 0; e < kExperts; ++e) {
      if (e == i1 || e == i2) continue;
      if (p[e] > v2) { v2 = p[e]; i2 = e; }
    }
    int s1 = atomicAdd(&counts[i1], 1);
    list_idx[i1 * kTokens + s1] = t;
    list_w [i1 * kTokens + s1] = v1 * inv;
    int s2 = atomicAdd(&counts[i2], 1);
    list_idx[i2 * kTokens + s2] = t;
    list_w [i2 * kTokens + s2] = v2 * inv;
  }
}

// ------------------- tile mapping helpers -------------------
__device__ __forceinline__ bool map_tile(const int* __restrict__ counts, int mt,
                                         int& e, int& lm, int& sb, int& ne)
{
  int tb = 0; sb = 0;
  for (e = 0; e < kExperts; ++e) {
    ne = counts[e];
    int tiles = (ne + BM - 1) / BM;
    if (mt < tb + tiles) { lm = mt - tb; return true; }
    tb += tiles; sb += ne;
  }
  return false;
}

__device__ __forceinline__ bool map_tile2(const int* __restrict__ counts, int mt,
                                          int& e, int& lm, int& sb, int& ne)
{
  int tb = 0; sb = 0;
  for (e = 0; e < kExperts; ++e) {
    ne = counts[e];
    int tiles = (ne + BM2 - 1) / BM2;
    if (mt < tb + tiles) { lm = mt - tb; return true; }
    tb += tiles; sb += ne;
  }
  return false;
}

// ------------- GU GEMM: 4-phase counted-vmcnt pipeline -------------
// 8 waves: wr = w>>2 selects A row-half (128 rows), wc = w&3 selects 32 cols.
// Per K-tile: P0 G-mh0 | P1 G-mh1 | P2 U-mh0 | P3 U-mh1, 16 MFMA each.
// Stage units of NEXT tile: A0@P0, A1@P1, B1@P2, B3@P3 (2 gloads each).
// Waits: vmcnt(4) end-P1, vmcnt(2) end-P3 (never 0 in loop).
__global__ __launch_bounds__(512, 2) void moe_gu2(
    const unsigned short* __restrict__ xb,
    const unsigned short* __restrict__ w1b, const unsigned short* __restrict__ w3b,
    const int* __restrict__ counts, const int* __restrict__ list_idx,
    unsigned short* __restrict__ hbuf)
{
  // shorts: A[b][h] at (b*2+h)*8192 | B1[b] at 32768+b*8192 | B3[b] at 49152+b*8192
  __shared__ unsigned short lds[65536];
  __shared__ int toks[BM2];

  const int tid = threadIdx.x;
  const int nt  = blockIdx.x / MAX_MT2;
  const int mt  = blockIdx.x % MAX_MT2;

  int e, lm, sb, ne;
  if (!map_tile2(counts, mt, e, lm, sb, ne)) return;
  const int row0 = lm * BM2;

  if (tid < BM2) {
    int lr = row0 + tid;
    toks[tid] = list_idx[e * kTokens + ((lr < ne) ? lr : 0)];
  }
  __syncthreads();

  const int lane = tid & 63;
  const int w    = tid >> 6;
  const int wr   = w >> 2;   // 0..1
  const int wc   = w & 3;    // 0..3

  // staging sources (chunk l = (w*2+i)*64+lane; r=l>>3, c=(l&7)^(r&7))
  const unsigned short* srcA[2][2];
  const unsigned short* srcB1[2];
  const unsigned short* srcB3[2];
  {
    const size_t bb = ((size_t)(e * (kInter / BN2) + nt) * (kHidden / BK2)) * 1024;
#pragma unroll
    for (int i = 0; i < 2; ++i) {
      int l = (w * 2 + i) * 64 + lane;
      int r = l >> 3, cs = l & 7, c = cs ^ (r & 7);
#pragma unroll
      for (int h = 0; h < 2; ++h)
        srcA[h][i] = xb + (size_t)toks[h * 128 + r] * kHidden + c * 8;
      srcB1[i] = w1b + (bb + l) * 8;
      srcB3[i] = w3b + (bb + l) * 8;
    }
  }

  f32x4 accG[8][2], accU[8][2];
  const f32x4 zero = {0.f, 0.f, 0.f, 0.f};
#pragma unroll
  for (int m = 0; m < 8; ++m)
#pragma unroll
    for (int n = 0; n < 2; ++n) { accG[m][n] = zero; accU[m][n] = zero; }

  // prologue: stage tile 0 into buf0, order A0,A1,B1,B3
#pragma unroll
  for (int i = 0; i < 2; ++i) gload16(srcA[0][i], &lds[0 * 8192 + (w * 2 + i) * 512]);
#pragma unroll
  for (int i = 0; i < 2; ++i) gload16(srcA[1][i], &lds[1 * 8192 + (w * 2 + i) * 512]);
#pragma unroll
  for (int i = 0; i < 2; ++i) gload16(srcB1[i], &lds[32768 + (w * 2 + i) * 512]);
#pragma unroll
  for (int i = 0; i < 2; ++i) gload16(srcB3[i], &lds[49152 + (w * 2 + i) * 512]);
  asm volatile("s_waitcnt vmcnt(2)" ::: "memory");
  __builtin_amdgcn_sched_barrier(0);
  __builtin_amdgcn_s_barrier();

  for (int t = 0; t < NT2; ++t) {
    const int cb = t & 1, nb = cb ^ 1;
    const int tn = (t + 1 < NT2) ? (t + 1) : (NT2 - 1);  // dummy re-stage on last
    const int Acur = (cb * 2 + wr) * 8192;
    const int B1c  = 32768 + cb * 8192;
    const int B3c  = 49152 + cb * 8192;
    const int An0  = (nb * 2 + 0) * 8192;
    const int An1  = (nb * 2 + 1) * 8192;
    const int B1n  = 32768 + nb * 8192;
    const int B3n  = 49152 + nb * 8192;

    bf16x8 a0[4][2], a1[4][2];
    {
      bf16x8 b1f[2][2];
      // ---------------- P0: G, m-half 0 ----------------
#pragma unroll
      for (int m = 0; m < 4; ++m) {
        const int r = m * 16 + (lane & 15);
#pragma unroll
        for (int kk = 0; kk < 2; ++kk) {
          const int cq = kk * 4 + (lane >> 4);
          a0[m][kk] = *reinterpret_cast<const bf16x8*>(&lds[Acur + r * 64 + ((cq ^ (r & 7)) << 3)]);
        }
      }
#pragma unroll
      for (int n = 0; n < 2; ++n) {
        const int r = wc * 32 + n * 16 + (lane & 15);
#pragma unroll
        for (int kk = 0; kk < 2; ++kk) {
          const int cq = kk * 4 + (lane >> 4);
          b1f[n][kk] = *reinterpret_cast<const bf16x8*>(&lds[B1c + r * 64 + ((cq ^ (r & 7)) << 3)]);
        }
      }
#pragma unroll
      for (int i = 0; i < 2; ++i) gload16(srcA[0][i] + tn * 64, &lds[An0 + (w * 2 + i) * 512]);
      __builtin_amdgcn_s_setprio(1);
#pragma unroll
      for (int m = 0; m < 4; ++m)
#pragma unroll
        for (int n = 0; n < 2; ++n)
#pragma unroll
          for (int kk = 0; kk < 2; ++kk)
            accG[m][n] = __builtin_amdgcn_mfma_f32_16x16x32_bf16(a0[m][kk], b1f[n][kk], accG[m][n], 0, 0, 0);
      __builtin_amdgcn_s_setprio(0);
      __builtin_amdgcn_sched_barrier(0);
      __builtin_amdgcn_s_barrier();

      // ---------------- P1: G, m-half 1 ----------------
#pragma unroll
      for (int m = 0; m < 4; ++m) {
        const int r = 64 + m * 16 + (lane & 15);
#pragma unroll
        for (int kk = 0; kk < 2; ++kk) {
          const int cq = kk * 4 + (lane >> 4);
          a1[m][kk] = *reinterpret_cast<const bf16x8*>(&lds[Acur + r * 64 + ((cq ^ (r & 7)) << 3)]);
        }
      }
#pragma unroll
      for (int i = 0; i < 2; ++i) gload16(srcA[1][i] + tn * 64, &lds[An1 + (w * 2 + i) * 512]);
      __builtin_amdgcn_s_setprio(1);
#pragma unroll
      for (int m = 0; m < 4; ++m)
#pragma unroll
        for (int n = 0; n < 2; ++n)
#pragma unroll
          for (int kk = 0; kk < 2; ++kk)
            accG[4 + m][n] = __builtin_amdgcn_mfma_f32_16x16x32_bf16(a1[m][kk], b1f[n][kk], accG[4 + m][n], 0, 0, 0);
      __builtin_amdgcn_s_setprio(0);
      __builtin_amdgcn_sched_barrier(0);
      asm volatile("s_waitcnt vmcnt(4)" ::: "memory");
      __builtin_amdgcn_s_barrier();
    }
    {
      bf16x8 b3f[2][2];
      // ---------------- P2: U, m-half 0 ----------------
#pragma unroll
      for (int n = 0; n < 2; ++n) {
        const int r = wc * 32 + n * 16 + (lane & 15);
#pragma unroll
        for (int kk = 0; kk < 2; ++kk) {
          const int cq = kk * 4 + (lane >> 4);
          b3f[n][kk] = *reinterpret_cast<const bf16x8*>(&lds[B3c + r * 64 + ((cq ^ (r & 7)) << 3)]);
        }
      }
#pragma unroll
      for (int i = 0; i < 2; ++i) gload16(srcB1[i] + (size_t)tn * 8192, &lds[B1n + (w * 2 + i) * 512]);
      __builtin_amdgcn_s_setprio(1);
#pragma unroll
      for (int m = 0; m < 4; ++m)
#pragma unroll
        for (int n = 0; n < 2; ++n)
#pragma unroll
          for (int kk = 0; kk < 2; ++kk)
            accU[m][n] = __builtin_amdgcn_mfma_f32_16x16x32_bf16(a0[m][kk], b3f[n][kk], accU[m][n], 0, 0, 0);
      __builtin_amdgcn_s_setprio(0);
      __builtin_amdgcn_sched_barrier(0);
      __builtin_amdgcn_s_barrier();

      // ---------------- P3: U, m-half 1 ----------------
#pragma unroll
      for (int i = 0; i < 2; ++i) gload16(srcB3[i] + (size_t)tn * 8192, &lds[B3n + (w * 2 + i) * 512]);
      __builtin_amdgcn_s_setprio(1);
#pragma unroll
      for (int m = 0; m < 4; ++m)
#pragma unroll
        for (int n = 0; n < 2; ++n)
#pragma unroll
          for (int kk = 0; kk < 2; ++kk)
            accU[4 + m][n] = __builtin_amdgcn_mfma_f32_16x16x32_bf16(a1[m][kk], b3f[n][kk], accU[4 + m][n], 0, 0, 0);
      __builtin_amdgcn_s_setprio(0);
      __builtin_amdgcn_sched_barrier(0);
      asm volatile("s_waitcnt vmcnt(2)" ::: "memory");
      __builtin_amdgcn_s_barrier();
    }
  }

  // epilogue: h = silu(g)*u
#pragma unroll
  for (int am = 0; am < 8; ++am) {
#pragma unroll
    for (int r = 0; r < 4; ++r) {
      int rloc = wr * 128 + am * 16 + ((lane >> 4) * 4) + r;
      int lrow = row0 + rloc;
      if (lrow < ne) {
        size_t base = (size_t)(sb + lrow) * kInter + (size_t)nt * BN2 + wc * 32 + (lane & 15);
#pragma unroll
        for (int n = 0; n < 2; ++n) {
          float g = accG[am][n][r];
          float u = accU[am][n][r];
          float hv = (g / (1.f + __expf(-g))) * u;
          hbuf[base + n * 16] = f2bf(hv);
        }
      }
    }
  }
}

// ---------------------------- Y GEMM (round-2 proven) ----------------------------
__global__ __launch_bounds__(256, 3) void moe_y(
    const unsigned short* __restrict__ hbuf,
    const unsigned short* __restrict__ w2b,
    const int* __restrict__ counts, const int* __restrict__ list_idx,
    const float* __restrict__ list_w,
    float* __restrict__ out)
{
  __shared__ unsigned short As[BM * BK];
  __shared__ unsigned short Bs[BN * BK];
  __shared__ int   toks[BM];
  __shared__ float cofs[BM];

  const int tid = threadIdx.x;
  const int nt  = blockIdx.x / MAX_MT;
  const int mt  = blockIdx.x % MAX_MT;

  int e, lm, sb, ne;
  if (!map_tile(counts, mt, e, lm, sb, ne)) return;
  const int row0 = lm * BM;

  if (tid < BM) {
    int lr = row0 + tid;
    bool v = lr < ne;
    toks[tid] = v ? list_idx[e * kTokens + lr] : 0;
    cofs[tid] = v ? list_w [e * kTokens + lr] : 0.f;
  }
  __syncthreads();

  const int lane = tid & 63;
  const int w = tid >> 6;
  const int wr = w >> 1, wc = w & 1;

  const unsigned short* srcA[4];
  const unsigned short* srcB2[4];
  const size_t bbase = ((size_t)(e * (kHidden / BN) + nt) * (kInter / BK)) * 1024;
#pragma unroll
  for (int i = 0; i < 4; ++i) {
    int l = (w * 4 + i) * 64 + lane;
    int r = l >> 3, cs = l & 7, c = cs ^ (r & 7);
    srcA[i]  = hbuf + (size_t)(sb + row0 + r) * kInter + c * 8;
    srcB2[i] = w2b  + (bbase + l) * 8;
  }

  f32x4 acc[4][4];
  const f32x4 zero = {0.f, 0.f, 0.f, 0.f};
#pragma unroll
  for (int m = 0; m < 4; ++m)
#pragma unroll
    for (int n = 0; n < 4; ++n) acc[m][n] = zero;

  for (int ks = 0; ks < kInter / BK; ++ks) {
#pragma unroll
    for (int i = 0; i < 4; ++i) {
      gload16(srcA[i]  + ks * BK,           &As[(w * 4 + i) * 512]);
      gload16(srcB2[i] + (size_t)ks * 8192, &Bs[(w * 4 + i) * 512]);
    }
    __syncthreads();
#pragma unroll
    for (int kk = 0; kk < 2; ++kk) {
      const int cq = kk * 4 + (lane >> 4);
      bf16x8 a[4], b[4];
#pragma unroll
      for (int m = 0; m < 4; ++m) {
        int row = wr * 64 + m * 16 + (lane & 15);
        a[m] = *reinterpret_cast<const bf16x8*>(&As[row * 64 + ((cq ^ (row & 7)) << 3)]);
      }
#pragma unroll
      for (int n = 0; n < 4; ++n) {
        int row = wc * 64 + n * 16 + (lane & 15);
        b[n] = *reinterpret_cast<const bf16x8*>(&Bs[row * 64 + ((cq ^ (row & 7)) << 3)]);
      }
#pragma unroll
      for (int m = 0; m < 4; ++m)
#pragma unroll
        for (int n = 0; n < 4; ++n)
          acc[m][n] = __builtin_amdgcn_mfma_f32_16x16x32_bf16(a[m], b[n], acc[m][n], 0, 0, 0);
    }
    __syncthreads();
  }

#pragma unroll
  for (int m = 0; m < 4; ++m) {
#pragma unroll
    for (int r = 0; r < 4; ++r) {
      int rloc = wr * 64 + m * 16 + ((lane >> 4) * 4) + r;
      if (row0 + rloc < ne) {
        float cf = cofs[rloc];
        size_t obase = (size_t)toks[rloc] * kHidden + (size_t)nt * BN + wc * 64 + (lane & 15);
#pragma unroll
        for (int n = 0; n < 4; ++n)
          atomicAdd(&out[obase + n * 16], cf * acc[m][n][r]);
      }
    }
  }
}

// ===================== fallback (fp32 on-the-fly) ============
__global__ __launch_bounds__(256, 2) void moe_gu_f32(
    const unsigned short* __restrict__ xb,
    const float* __restrict__ w1, const float* __restrict__ w3,
    const int* __restrict__ counts, const int* __restrict__ list_idx,
    unsigned short* __restrict__ hbuf)
{
  __shared__ unsigned short As [BM * BK];
  __shared__ unsigned short B1s[BN * BK];
  __shared__ unsigned short B3s[BN * BK];
  __shared__ int toks[BM];

  const int tid = threadIdx.x;
  const int nt  = blockIdx.x / MAX_MT;
  const int mt  = blockIdx.x % MAX_MT;

  int e, lm, sb, ne;
  if (!map_tile(counts, mt, e, lm, sb, ne)) return;
  const int row0 = lm * BM;

  if (tid < BM) {
    int lr = row0 + tid;
    toks[tid] = list_idx[e * kTokens + ((lr < ne) ? lr : 0)];
  }
  __syncthreads();

  const unsigned short* aptr[4];
#pragma unroll
  for (int i = 0; i < 4; ++i) {
    int chunk = i * 256 + tid;
    int r = chunk >> 3, c8 = chunk & 7;
    aptr[i] = xb + (size_t)toks[r] * kHidden + c8 * 8;
  }
  const float* w1e = w1 + (size_t)e * kInter * kHidden;
  const float* w3e = w3 + (size_t)e * kInter * kHidden;

  f32x4 accG[4][4], accU[4][4];
  const f32x4 zero = {0.f, 0.f, 0.f, 0.f};
#pragma unroll
  for (int m = 0; m < 4; ++m)
#pragma unroll
    for (int n = 0; n < 4; ++n) { accG[m][n] = zero; accU[m][n] = zero; }

  const int lane = tid & 63;
  const int wr = (tid >> 6) >> 1;
  const int wc = (tid >> 6) & 1;

  for (int k0 = 0; k0 < kHidden; k0 += BK) {
#pragma unroll
    for (int i = 0; i < 4; ++i) {
      int chunk = i * 256 + tid;
      uint4 v = *reinterpret_cast<const uint4*>(aptr[i] + k0);
      *reinterpret_cast<uint4*>(&As[chunk * 8]) = v;
    }
#pragma unroll
    for (int i = 0; i < 8; ++i) {
      int c = i * 256 + tid;
      int rowB = c >> 4, c16 = c & 15;
      size_t off = ((size_t)(nt * BN + rowB)) * kHidden + k0 + c16 * 4;
      float4 v1 = *reinterpret_cast<const float4*>(w1e + off);
      float4 v3 = *reinterpret_cast<const float4*>(w3e + off);
      uint2 p1, p3;
      p1.x = (u32)f2bf(v1.x) | ((u32)f2bf(v1.y) << 16);
      p1.y = (u32)f2bf(v1.z) | ((u32)f2bf(v1.w) << 16);
      p3.x = (u32)f2bf(v3.x) | ((u32)f2bf(v3.y) << 16);
      p3.y = (u32)f2bf(v3.z) | ((u32)f2bf(v3.w) << 16);
      *reinterpret_cast<uint2*>(&B1s[rowB * BK + c16 * 4]) = p1;
      *reinterpret_cast<uint2*>(&B3s[rowB * BK + c16 * 4]) = p3;
    }
    __syncthreads();
#pragma unroll
    for (int kk = 0; kk < 2; ++kk) {
      const int klo = kk * 32 + (lane >> 4) * 8;
      bf16x8 a[4], b1v[4], b3v[4];
#pragma unroll
      for (int m = 0; m < 4; ++m)
        a[m] = *reinterpret_cast<const bf16x8*>(&As[(wr * 64 + m * 16 + (lane & 15)) * BK + klo]);
#pragma unroll
      for (int n = 0; n < 4; ++n) {
        b1v[n] = *reinterpret_cast<const bf16x8*>(&B1s[(wc * 64 + n * 16 + (lane & 15)) * BK + klo]);
        b3v[n] = *reinterpret_cast<const bf16x8*>(&B3s[(wc * 64 + n * 16 + (lane & 15)) * BK + klo]);
      }
#pragma unroll
      for (int m = 0; m < 4; ++m)
#pragma unroll
        for (int n = 0; n < 4; ++n) {
          accG[m][n] = __builtin_amdgcn_mfma_f32_16x16x32_bf16(a[m], b1v[n], accG[m][n], 0, 0, 0);
          accU[m][n] = __builtin_amdgcn_mfma_f32_16x16x32_bf16(a[m], b3v[n], accU[m][n], 0, 0, 0);
        }
    }
    __syncthreads();
  }
#pragma unroll
  for (int m = 0; m < 4; ++m) {
#pragma unroll
    for (int r = 0; r < 4; ++r) {
      int rloc = wr * 64 + m * 16 + ((lane >> 4) * 4) + r;
      int lrow = row0 + rloc;
      if (lrow < ne) {
        size_t base = (size_t)(sb + lrow) * kInter + (size_t)nt * BN + wc * 64 + (lane & 15);
#pragma unroll
        for (int n = 0; n < 4; ++n) {
          float g = accG[m][n][r];
          float u = accU[m][n][r];
          hbuf[base + n * 16] = f2bf((g / (1.f + __expf(-g))) * u);
        }
      }
    }
  }
}

__global__ __launch_bounds__(256, 2) void moe_y_f32(
    const unsigned short* __restrict__ hbuf,
    const float* __restrict__ w2,
    const int* __restrict__ counts, const int* __restrict__ list_idx,
    const float* __restrict__ list_w,
    float* __restrict__ out)
{
  __shared__ unsigned short As[BM * BK];
  __shared__ unsigned short Bs[BN * BK];
  __shared__ int   toks[BM];
  __shared__ float cofs[BM];

  const int tid = threadIdx.x;
  const int nt  = blockIdx.x / MAX_MT;
  const int mt  = blockIdx.x % MAX_MT;

  int e, lm, sb, ne;
  if (!map_tile(counts, mt, e, lm, sb, ne)) return;
  const int row0 = lm * BM;

  if (tid < BM) {
    int lr = row0 + tid;
    bool v = lr < ne;
    toks[tid] = v ? list_idx[e * kTokens + lr] : 0;
    cofs[tid] = v ? list_w [e * kTokens + lr] : 0.f;
  }
  __syncthreads();

  const float* w2e = w2 + (size_t)e * kHidden * kInter;
  const unsigned short* arow = hbuf + (size_t)(sb + row0) * kInter;

  f32x4 acc[4][4];
  const f32x4 zero = {0.f, 0.f, 0.f, 0.f};
#pragma unroll
  for (int m = 0; m < 4; ++m)
#pragma unroll
    for (int n = 0; n < 4; ++n) acc[m][n] = zero;

  const int lane = tid & 63;
  const int wr = (tid >> 6) >> 1;
  const int wc = (tid >> 6) & 1;

  for (int k0 = 0; k0 < kInter; k0 += BK) {
#pragma unroll
    for (int i = 0; i < 4; ++i) {
      int chunk = i * 256 + tid;
      int r = chunk >> 3, c8 = chunk & 7;
      uint4 v = *reinterpret_cast<const uint4*>(arow + (size_t)r * kInter + k0 + c8 * 8);
      *reinterpret_cast<uint4*>(&As[chunk * 8]) = v;
    }
#pragma unroll
    for (int i = 0; i < 8; ++i) {
      int c = i * 256 + tid;
      int rowB = c >> 4, c16 = c & 15;
      size_t off = ((size_t)(nt * BN + rowB)) * kInter + k0 + c16 * 4;
      float4 v2 = *reinterpret_cast<const float4*>(w2e + off);
      uint2 p2;
      p2.x = (u32)f2bf(v2.x) | ((u32)f2bf(v2.y) << 16);
      p2.y = (u32)f2bf(v2.z) | ((u32)f2bf(v2.w) << 16);
      *reinterpret_cast<uint2*>(&Bs[rowB * BK + c16 * 4]) = p2;
    }
    __syncthreads();
#pragma unroll
    for (int kk = 0; kk < 2; ++kk) {
      const int klo = kk * 32 + (lane >> 4) * 8;
      bf16x8 a[4], b[4];
#pragma unroll
      for (int m = 0; m < 4; ++m)
        a[m] = *reinterpret_cast<const bf16x8*>(&As[(wr * 64 + m * 16 + (lane & 15)) * BK + klo]);
#pragma unroll
      for (int n = 0; n < 4; ++n)
        b[n] = *reinterpret_cast<const bf16x8*>(&Bs[(wc * 64 + n * 16 + (lane & 15)) * BK + klo]);
#pragma unroll
      for (int m = 0; m < 4; ++m)
#pragma unroll
        for (int n = 0; n < 4; ++n)
          acc[m][n] = __builtin_amdgcn_mfma_f32_16x16x32_bf16(a[m], b[n], acc[m][n], 0, 0, 0);
    }
    __syncthreads();
  }
#pragma unroll
  for (int m = 0; m < 4; ++m) {
#pragma unroll
    for (int r = 0; r < 4; ++r) {
      int rloc = wr * 64 + m * 16 + ((lane >> 4) * 4) + r;
      if (row0 + rloc < ne) {
        float cf = cofs[rloc];
        size_t obase = (size_t)toks[rloc] * kHidden + (size_t)nt * BN + wc * 64 + (lane & 15);
#pragma unroll
        for (int n = 0; n < 4; ++n)
          atomicAdd(&out[obase + n * 16], cf * acc[m][n][r]);
      }
    }
  }
}

// ---------------------------- host ----------------------------
extern "C" void kernel_launch(void* const* d_in, const int* in_sizes, int n_in,
                              void* d_out, int out_size, void* d_ws, size_t ws_size,
                              hipStream_t stream)
{
  const float* x      = (const float*)d_in[0];
  const float* gate_w = (const float*)d_in[1];
  const float* w1     = (const float*)d_in[2];
  const float* w2     = (const float*)d_in[3];
  const float* w3     = (const float*)d_in[4];
  float* out = (float*)d_out;

  char* ws = (char*)d_ws;
  const size_t MiB = 1ull << 20;
  int*   counts   = (int*)(ws);
  int*   list_idx = (int*)(ws + 1024);
  float* list_w   = (float*)(ws + 1024 + kExperts * kTokens * 4);

  hipMemsetAsync(counts, 0, 1024, stream);
  hipMemsetAsync(out, 0, (size_t)kTokens * kHidden * sizeof(float), stream);

  if (ws_size >= 418 * MiB) {
    unsigned short* xb   = (unsigned short*)(ws + 1 * MiB);
    unsigned short* w1b  = (unsigned short*)(ws + 33 * MiB);
    unsigned short* w3b  = (unsigned short*)(ws + 161 * MiB);
    unsigned short* hbuf = (unsigned short*)(ws + 289 * MiB);
    unsigned short* w2b  = w1b;  // reuse after GU

    const long nch = (long)kExperts * (kInter / BN) * (kHidden / BK) * 1024;
    convert_w<<<4096, 256, 0, stream>>>(w1, w1b, 5, 5, kHidden, nch);
    convert_w<<<4096, 256, 0, stream>>>(w3, w3b, 5, 5, kHidden, nch);
    moe_router<<<kTokens / 4, 256, 0, stream>>>(x, gate_w, xb, counts, list_idx, list_w);
    moe_gu2<<<(kInter / BN2) * MAX_MT2, 512, 0, stream>>>(xb, w1b, w3b, counts, list_idx, hbuf);
    convert_w<<<4096, 256, 0, stream>>>(w2, w2b, 4, 6, kInter, nch);
    moe_y<<<(kHidden / BN) * MAX_MT, 256, 0, stream>>>(hbuf, w2b, counts, list_idx, list_w, out);
  } else {
    unsigned short* xb   = (unsigned short*)(ws + 1 * MiB);
    unsigned short* hbuf = (unsigned short*)(ws + 36 * MiB);
    moe_router<<<kTokens / 4, 256, 0, stream>>>(x, gate_w, xb, counts, list_idx, list_w);
    moe_gu_f32<<<(kInter / BN) * MAX_MT, 256, 0, stream>>>(xb, w1, w3, counts, list_idx, hbuf);
    moe_y_f32 <<<(kHidden / BN) * MAX_MT, 256, 0, stream>>>(hbuf, w2, counts, list_idx, list_w, out);
  }
}